// Round 10
// baseline (342.232 us; speedup 1.0000x reference)
//
#include <hip/hip_runtime.h>
#include <hip/hip_bf16.h>

// ---------------------------------------------------------------------------
// DRRGHead, 9 dispatches.
//   relu(cat(x_norm, A@x_norm) @ W + b) == relu(x@W' + b' + A@(x@W'_bot))
// BN folded into W1; K1 fused cast+stats; K3 all weight repacks.
// GEMM: 256x128 MFMA tile (R9: was 128x128 — 2-phase stall amortizes over 2x
//   MFMA/barrier), 2-ph dbuf global_load_lds, supergroup swizzle, LDS
//   slot-swizzle via pre-swizzled global source (conflict-free ds_read_b128).
// G4F: gemm4+agg4+classifier fused, P in LDS only.
// ---------------------------------------------------------------------------

using f32x4 = __attribute__((ext_vector_type(4))) float;
using s16x8 = __attribute__((ext_vector_type(8))) short;   // 8 bf16

#define GN 20992          // G*N rows (= 82*256 = 256*82 exactly)
#define NFEAT 576
#define NGRAPH 512
#define NNODE 41
#define NTM2 82           // m-tiles of 256

typedef __attribute__((address_space(1))) const unsigned int gas_u32;
typedef __attribute__((address_space(3))) unsigned int las_u32;

__device__ __forceinline__ void gl_lds16(const void* g, void* l) {
  __builtin_amdgcn_global_load_lds((gas_u32*)g, (las_u32*)l, 16, 0, 0);
}

// ---------------- K1: fused bf16-cast + bn-stats (one pass over nf) ---------
__global__ __launch_bounds__(576) void front_kernel(
    const float* __restrict__ nf, float* __restrict__ partial,
    __hip_bfloat16* __restrict__ x0) {
  int c = threadIdx.x;                  // 0..575
  int u = blockIdx.x;                   // 0..255
  int r0 = u * 82;
  const float* src = nf + (size_t)r0 * NFEAT + c;
  __hip_bfloat16* dst = x0 + (size_t)r0 * NFEAT + c;
  float s = 0.f, s2 = 0.f;
#pragma unroll 4
  for (int r = 0; r < 82; ++r) {
    float v = src[(size_t)r * NFEAT];
    s += v; s2 += v * v;
    dst[(size_t)r * NFEAT] = __float2bfloat16(v);
  }
  partial[(size_t)u * 1152 + c] = s;
  partial[(size_t)u * 1152 + NFEAT + c] = s2;
}

// ---------------- K2: wide BN reduce -> statsbuf = {inv[576], m*inv[576]} ---
__global__ __launch_bounds__(256) void reduce_kernel(
    const float* __restrict__ partial, float* __restrict__ statsbuf) {
  int t = blockIdx.x * 256 + threadIdx.x;
  if (t >= NFEAT) return;
  float s = 0.f, s2 = 0.f;
#pragma unroll 8
  for (int u = 0; u < 256; ++u) {
    s += partial[(size_t)u * 1152 + t];
    s2 += partial[(size_t)u * 1152 + NFEAT + t];
  }
  float m = s * (1.f / GN);
  float v = s2 * (1.f / GN) - m * m;
  float inv = rsqrtf(v + 1e-5f);
  statsbuf[t] = inv;
  statsbuf[NFEAT + t] = m * inv;
}

// ---------------- K3: W1 fold-repack + cvec GEMV + W2-4 repack --------------
__global__ __launch_bounds__(256) void wt1_kernel(
    const float* __restrict__ W1, const float* __restrict__ b1,
    const float* __restrict__ statsbuf, __hip_bfloat16* __restrict__ B1,
    float* __restrict__ gbias,
    const float* __restrict__ W2, const float* __restrict__ W3,
    const float* __restrict__ W4,
    __hip_bfloat16* __restrict__ B2, __hip_bfloat16* __restrict__ B3,
    __hip_bfloat16* __restrict__ B4) {
  int u = blockIdx.x;
  int tid = threadIdx.x;
  if (u < 576) {                        // fold-repack tile of W1
    __shared__ float T[32 * 33];
    int jt = u / 18, kt = u - jt * 18;
    int j0 = jt * 32, k0 = kt * 32;
    int h = (j0 >= 512) ? 1 : 0;
    const float* Wh = W1 + (size_t)(h * 576) * 512 + (j0 - h * 512);
    int r = tid >> 5, cc = tid & 31;
#pragma unroll
    for (int i = 0; i < 4; ++i)
      T[(r + i * 8) * 33 + cc] = Wh[(size_t)(k0 + r + i * 8) * 512 + cc];
    __syncthreads();
    float invv = statsbuf[k0 + cc];
#pragma unroll
    for (int i = 0; i < 4; ++i)
      B1[(size_t)(j0 + r + i * 8) * 576 + k0 + cc] =
          __float2bfloat16(T[cc * 33 + (r + i * 8)] * invv);
  } else if (u < 580) {                 // cvec GEMV
    int j = (u - 576) * 256 + tid;      // 0..1023
    int col = (j < 512) ? j : j - 512;
    const float* base = W1 + (size_t)((j < 512) ? 0 : 576) * 512 + col;
    float s = 0.f;
#pragma unroll 4
    for (int f = 0; f < NFEAT; ++f) s += statsbuf[NFEAT + f] * base[(size_t)f * 512];
    gbias[j] = ((j < 512) ? b1[j] : 0.f) - s;
  } else {                              // plain repack W2/W3/W4
    __shared__ float T[32 * 33];
    int t = u - 580;
    const float* W; __hip_bfloat16* B; int K, N;
    if (t < 256)      { W = W2; B = B2; K = 512; N = 256; }
    else if (t < 320) { W = W3; B = B3; K = 256; N = 128; t -= 256; }
    else              { W = W4; B = B4; K = 128; N = 64;  t -= 320; }
    int tilesN = N >> 5;
    int perhalf = (K >> 5) * tilesN;
    int h = t / perhalf; t -= h * perhalf;
    int tk = t / tilesN, tn = t - tk * tilesN;
    int r = tid >> 5, cc = tid & 31;
    const float* Wh = W + (size_t)h * K * N;
#pragma unroll
    for (int i = 0; i < 4; ++i)
      T[(r + i * 8) * 33 + cc] = Wh[(size_t)(tk * 32 + r + i * 8) * N + tn * 32 + cc];
    __syncthreads();
    __hip_bfloat16* Bh = B + (size_t)h * N * K;
#pragma unroll
    for (int i = 0; i < 4; ++i)
      Bh[(size_t)(tn * 32 + r + i * 8) * K + tk * 32 + cc] =
          __float2bfloat16(T[cc * 33 + r + i * 8]);
  }
}

// ---------------- MFMA bf16 GEMM: P = x @ Bt^T (+bias on cols < biasN) ------
// 256x128 tile, 4 waves 2x2 (per-wave 128x64 = 8x4 fragments), 2-ph dbuf,
// slot-swizzled LDS via pre-swizzled global source.
__global__ __launch_bounds__(256, 2) void gemm_kernel(
    const __hip_bfloat16* __restrict__ Xptr, const __hip_bfloat16* __restrict__ Bt,
    const float* __restrict__ bias, int biasN,
    __hip_bfloat16* __restrict__ Pptr, int Np, int K, int NTN,
    const float* __restrict__ cinputs, const float* __restrict__ conv_w,
    const float* __restrict__ conv_b, float* __restrict__ cout) {
  __shared__ short Ash[2][256 * 32];    // 32 KB
  __shared__ short Bsh[2][128 * 32];    // 16 KB
  int tid = threadIdx.x;
  int bid = blockIdx.x;
  int gemmBlocks = NTM2 * NTN;

  if (bid >= gemmBlocks) {              // ---- conv pool (tail filler)
    int p = (bid - gemmBlocks) * 256 + tid;
    int img = p >> 16, q = p & 65535;
    const float4* ip = (const float4*)cinputs + (size_t)img * 32 * 65536 + q;
    float4 acc[6];
#pragma unroll
    for (int o = 0; o < 6; ++o) { float b0 = conv_b[o]; acc[o] = make_float4(b0, b0, b0, b0); }
#pragma unroll 4
    for (int c = 0; c < 32; ++c) {
      float4 x = ip[(size_t)c * 65536];
#pragma unroll
      for (int o = 0; o < 6; ++o) {
        float wv = conv_w[o * 32 + c];
        acc[o].x += x.x * wv; acc[o].y += x.y * wv;
        acc[o].z += x.z * wv; acc[o].w += x.w * wv;
      }
    }
    float4* op = (float4*)cout + (size_t)img * 6 * 65536 + q;
#pragma unroll
    for (int o = 0; o < 6; ++o) op[(size_t)o * 65536] = acc[o];
    return;
  }

  int sg = bid / (NTN * 8);
  int rem = bid - sg * (NTN * 8);
  int Wm = NTM2 - sg * 8; if (Wm > 8) Wm = 8;
  int mt = sg * 8 + rem % Wm;
  int nt = rem / Wm;
  int m0 = mt * 256, n0 = nt * 128;

  int wave = tid >> 6, lane = tid & 63;
  int wm = wave >> 1, wn = wave & 1;
  int lr = lane & 15, kb = lane >> 4;

  f32x4 acc[8][4];
#pragma unroll
  for (int m = 0; m < 8; ++m)
#pragma unroll
    for (int n = 0; n < 4; ++n) acc[m][n] = (f32x4){0.f, 0.f, 0.f, 0.f};

  const short* Ag = (const short*)Xptr + (size_t)m0 * K;
  const short* Bg = (const short*)Bt + (size_t)n0 * K;

  // staging: A tile 256x32 = 1024 chunks (4/thread); B 128x32 = 512 (2/thread)
  // slot c holds global chunk (row = c>>2, k-chunk = (c&3)^((row>>1)&3))
  int ca[4], ara[4], aka[4];
#pragma unroll
  for (int i = 0; i < 4; ++i) {
    ca[i] = tid + i * 256;
    ara[i] = ca[i] >> 2;
    aka[i] = ((ca[i] & 3) ^ ((ara[i] >> 1) & 3)) * 8;
  }
  int cb0 = tid, cb1 = tid + 256;
  int br0 = cb0 >> 2, bk0 = ((cb0 & 3) ^ ((br0 >> 1) & 3)) * 8;
  int br1 = cb1 >> 2, bk1 = ((cb1 & 3) ^ ((br1 >> 1) & 3)) * 8;

  // fragment read offsets (shorts): row*32 + (((row>>1)&3)^kb)*8
  int aoff[8], boff[4];
#pragma unroll
  for (int m = 0; m < 8; ++m) {
    int r = wm * 128 + m * 16 + lr;
    aoff[m] = r * 32 + ((((r >> 1) & 3) ^ kb) * 8);
  }
#pragma unroll
  for (int n = 0; n < 4; ++n) {
    int r = wn * 64 + n * 16 + lr;
    boff[n] = r * 32 + ((((r >> 1) & 3) ^ kb) * 8);
  }

#pragma unroll
  for (int i = 0; i < 4; ++i)
    gl_lds16(Ag + (size_t)ara[i] * K + aka[i], &Ash[0][ca[i] * 8]);
  gl_lds16(Bg + (size_t)br0 * K + bk0, &Bsh[0][cb0 * 8]);
  gl_lds16(Bg + (size_t)br1 * K + bk1, &Bsh[0][cb1 * 8]);
  __syncthreads();

  int nkt = K >> 5;
  int cur = 0;
  for (int kt = 0; kt < nkt; ++kt) {
    if (kt + 1 < nkt) {
      int k1 = (kt + 1) * 32;
#pragma unroll
      for (int i = 0; i < 4; ++i)
        gl_lds16(Ag + (size_t)ara[i] * K + k1 + aka[i], &Ash[cur ^ 1][ca[i] * 8]);
      gl_lds16(Bg + (size_t)br0 * K + k1 + bk0, &Bsh[cur ^ 1][cb0 * 8]);
      gl_lds16(Bg + (size_t)br1 * K + k1 + bk1, &Bsh[cur ^ 1][cb1 * 8]);
    }
    s16x8 af[8], bfr[4];
#pragma unroll
    for (int m = 0; m < 8; ++m) af[m] = *(const s16x8*)&Ash[cur][aoff[m]];
#pragma unroll
    for (int n = 0; n < 4; ++n) bfr[n] = *(const s16x8*)&Bsh[cur][boff[n]];
#pragma unroll
    for (int m = 0; m < 8; ++m)
#pragma unroll
      for (int n = 0; n < 4; ++n)
        acc[m][n] = __builtin_amdgcn_mfma_f32_16x16x32_bf16(af[m], bfr[n], acc[m][n], 0, 0, 0);
    __syncthreads();
    cur ^= 1;
  }

  int rbase = (lane >> 4) * 4;
#pragma unroll
  for (int m = 0; m < 8; ++m) {
    int row = m0 + wm * 128 + m * 16 + rbase;
#pragma unroll
    for (int n = 0; n < 4; ++n) {
      int col = n0 + wn * 64 + n * 16 + lr;
      float bv = (col < biasN) ? bias[col] : 0.f;
#pragma unroll
      for (int r = 0; r < 4; ++r) {
        float v = acc[m][n][r] + bv;
        Pptr[(size_t)(row + r) * Np + col] = __float2bfloat16(v);
      }
    }
  }
}

// ---------------- fused agg epilogue: y = relu(P_L + A @ P_R), L1-L3 --------
template <int N>
__global__ __launch_bounds__(256) void aggep_kernel(
    const __hip_bfloat16* __restrict__ P, const float* __restrict__ Aadj,
    __hip_bfloat16* __restrict__ Y) {
  constexpr int GPB = (N >= 256) ? 1 : (256 / N);
  __shared__ float Ash[GPB * NNODE * NNODE];
  int g0 = blockIdx.x * GPB;
  for (int i = threadIdx.x; i < GPB * NNODE * NNODE; i += 256)
    Ash[i] = Aadj[(size_t)g0 * (NNODE * NNODE) + i];
  __syncthreads();

  int sub, c;
  if constexpr (GPB == 1) { sub = 0; c = threadIdx.x; }
  else { sub = threadIdx.x / N; c = threadIdx.x % N; }
  const float* Am = &Ash[sub * NNODE * NNODE];
  const __hip_bfloat16* Pg = P + (size_t)(g0 + sub) * NNODE * (2 * N);
  __hip_bfloat16* Yg = Y + (size_t)(g0 + sub) * NNODE * N;

  for (; c < N; c += 256) {
    float pr[NNODE];
#pragma unroll
    for (int m = 0; m < NNODE; ++m)
      pr[m] = __bfloat162float(Pg[(size_t)m * (2 * N) + N + c]);
#pragma unroll 1
    for (int n = 0; n < NNODE; ++n) {
      float aa = __bfloat162float(Pg[(size_t)n * (2 * N) + c]);
#pragma unroll
      for (int m = 0; m < NNODE; ++m) aa += Am[n * NNODE + m] * pr[m];
      aa = aa > 0.f ? aa : 0.f;
      Yg[(size_t)n * N + c] = __float2bfloat16(aa);
    }
    if constexpr (GPB > 1) break;
  }
}

// ---------------- G4F: gemm4 + agg4 + knn classifier, 3 graphs/block --------
__global__ __launch_bounds__(256) void gemm4cls_kernel(
    const __hip_bfloat16* __restrict__ X, const __hip_bfloat16* __restrict__ B4t,
    const float* __restrict__ b4, const float* __restrict__ Aadj,
    const int* __restrict__ knn, const float* __restrict__ w1,
    const float* __restrict__ cb1, const float* __restrict__ pa,
    const float* __restrict__ w2, const float* __restrict__ cb2,
    float* __restrict__ out) {
  __shared__ __align__(16) char smem[49152 + 20172 + 31488 + 8192 + 520];
  short* AshD = (short*)smem;
  short* Bsh  = (short*)(smem + 16384);
  __hip_bfloat16* Psh = (__hip_bfloat16*)smem;
  float* Aash = (float*)(smem + 49152);
  float* Ysh  = (float*)(smem + 49152 + 20172);
  float* Wsh  = (float*)(smem + 49152 + 20172 + 31488);
  float* cb   = (float*)(smem + 49152 + 20172 + 31488 + 8192);

  int tid = threadIdx.x;
  int blk = blockIdx.x;
  int g0 = blk * 3;
  int gcnt = NGRAPH - g0; if (gcnt > 3) gcnt = 3;
  int row0 = blk * 123;

  for (int i = tid; i < gcnt * NNODE * NNODE; i += 256)
    Aash[i] = Aadj[(size_t)g0 * (NNODE * NNODE) + i];
  for (int i = tid; i < 2048; i += 256) Wsh[i] = w1[i];
  if (tid < 32) { cb[tid] = cb1[tid]; cb[32 + tid] = pa[tid]; }
  if (tid < 64) cb[64 + tid] = w2[tid];
  if (tid < 2) cb[128 + tid] = cb2[tid];

  // stage whole B4t (4 ktiles), slot-swizzled within each ktile
#pragma unroll
  for (int i = 0; i < 8; ++i) {
    int c = tid + i * 256;              // 2048 chunks of 16B
    int kt = c >> 9, w = c & 511;
    int r = w >> 2, kc = ((w & 3) ^ ((r >> 1) & 3)) * 8;
    gl_lds16((const short*)B4t + (size_t)r * 128 + kt * 32 + kc, &Bsh[c * 8]);
  }
  // stage A k-tile 0 (swizzled)
  const short* Ag = (const short*)X;
  int c0 = tid, c1 = tid + 256;
  int ar0 = c0 >> 2, ak0 = (((c0 & 3) ^ ((ar0 >> 1) & 3))) * 8;
  int ar1 = c1 >> 2, ak1 = (((c1 & 3) ^ ((ar1 >> 1) & 3))) * 8;
  int grow0 = row0 + ar0; if (grow0 > GN - 1) grow0 = GN - 1;
  int grow1 = row0 + ar1; if (grow1 > GN - 1) grow1 = GN - 1;
  gl_lds16(Ag + (size_t)grow0 * 128 + ak0, &AshD[c0 * 8]);
  gl_lds16(Ag + (size_t)grow1 * 128 + ak1, &AshD[c1 * 8]);
  __syncthreads();

  int wave = tid >> 6, lane = tid & 63;
  int wm = wave >> 1, wn = wave & 1;
  int lr = lane & 15, kb = lane >> 4;
  int aoff[4], boff[4];
#pragma unroll
  for (int m = 0; m < 4; ++m) {
    int r = wm * 64 + m * 16 + lr;
    aoff[m] = r * 32 + ((((r >> 1) & 3) ^ kb) * 8);
  }
#pragma unroll
  for (int n = 0; n < 4; ++n) {
    int r = wn * 64 + n * 16 + lr;
    boff[n] = r * 32 + ((((r >> 1) & 3) ^ kb) * 8);
  }
  f32x4 acc[4][4];
#pragma unroll
  for (int m = 0; m < 4; ++m)
#pragma unroll
    for (int n = 0; n < 4; ++n) acc[m][n] = (f32x4){0.f, 0.f, 0.f, 0.f};

  int cur = 0;
  for (int kt = 0; kt < 4; ++kt) {
    if (kt < 3) {
      int k1 = (kt + 1) * 32;
      int nxt = (cur ^ 1) * 4096;
      gl_lds16(Ag + (size_t)grow0 * 128 + k1 + ak0, &AshD[nxt + c0 * 8]);
      gl_lds16(Ag + (size_t)grow1 * 128 + k1 + ak1, &AshD[nxt + c1 * 8]);
    }
    int cbse = cur * 4096;
    s16x8 af[4], bfr[4];
#pragma unroll
    for (int m = 0; m < 4; ++m) af[m] = *(const s16x8*)&AshD[cbse + aoff[m]];
#pragma unroll
    for (int n = 0; n < 4; ++n) bfr[n] = *(const s16x8*)&Bsh[kt * 4096 + boff[n]];
#pragma unroll
    for (int m = 0; m < 4; ++m)
#pragma unroll
      for (int n = 0; n < 4; ++n)
        acc[m][n] = __builtin_amdgcn_mfma_f32_16x16x32_bf16(af[m], bfr[n], acc[m][n], 0, 0, 0);
    __syncthreads();
    cur ^= 1;
  }
  // epilogue -> Psh (overlays staging LDS; safe after the barrier above)
  int rbase = (lane >> 4) * 4;
#pragma unroll
  for (int m = 0; m < 4; ++m) {
    int lrow = wm * 64 + m * 16 + rbase;
#pragma unroll
    for (int n = 0; n < 4; ++n) {
      int col = wn * 64 + n * 16 + lr;
      float bv = (col < 64) ? b4[col] : 0.f;
#pragma unroll
      for (int r = 0; r < 4; ++r)
        Psh[(size_t)(lrow + r) * 128 + col] = __float2bfloat16(acc[m][n][r] + bv);
    }
  }
  __syncthreads();

  // agg: y[g][n][c] = relu(P[g*41+n][c] + sum_m A[g][n][m] * P[g*41+m][64+c])
  int c = tid & 63, grp = tid >> 6;
  for (int g = 0; g < gcnt; ++g) {
    float pr[NNODE];
    const __hip_bfloat16* Pb = Psh;
#pragma unroll
    for (int m = 0; m < NNODE; ++m)
      pr[m] = __bfloat162float(Pb[(size_t)(g * NNODE + m) * 128 + 64 + c]);
    const float* Am = Aash + g * NNODE * NNODE;
#pragma unroll 1
    for (int n = grp; n < NNODE; n += 4) {
      float aa = __bfloat162float(Pb[(size_t)(g * NNODE + n) * 128 + c]);
#pragma unroll
      for (int m = 0; m < NNODE; ++m) aa += Am[n * NNODE + m] * pr[m];
      Ysh[(g * NNODE + n) * 64 + c] = aa > 0.f ? aa : 0.f;
    }
  }
  __syncthreads();

  // classifier: 8*gcnt edges, 32 lanes each
  int j = tid & 31, slot = tid >> 5;
  for (int el = slot; el < 8 * gcnt; el += 8) {
    int e = g0 * 8 + el;
    int node = knn[e];
    int gl = el >> 3;
    const float* fp = &Ysh[(gl * NNODE + node) * 64];
    float a2 = cb[j];
#pragma unroll
    for (int d = 0; d < 64; ++d) a2 += fp[d] * Wsh[d * 32 + j];
    float h = a2 >= 0.f ? a2 : cb[32 + j] * a2;
#pragma unroll
    for (int o = 0; o < 2; ++o) {
      float v = h * cb[64 + j * 2 + o];
      v += __shfl_xor(v, 16, 32); v += __shfl_xor(v, 8, 32);
      v += __shfl_xor(v, 4, 32);  v += __shfl_xor(v, 2, 32);
      v += __shfl_xor(v, 1, 32);
      if (j == 0) out[(size_t)e * 2 + o] = v;
    }
  }
}

// ---------------------------------------------------------------------------
extern "C" void kernel_launch(void* const* d_in, const int* in_sizes, int n_in,
                              void* d_out, int out_size, void* d_ws, size_t ws_size,
                              hipStream_t stream) {
  const float* inputs     = (const float*)d_in[0];
  const float* node_feats = (const float*)d_in[1];
  const float* Aadj       = (const float*)d_in[2];
  const int*   knn        = (const int*)d_in[3];
  const float* conv_w     = (const float*)d_in[4];
  const float* conv_b     = (const float*)d_in[5];
  const float* W1 = (const float*)d_in[6];  const float* b1 = (const float*)d_in[7];
  const float* W2 = (const float*)d_in[8];  const float* b2 = (const float*)d_in[9];
  const float* W3 = (const float*)d_in[10]; const float* b3 = (const float*)d_in[11];
  const float* W4 = (const float*)d_in[12]; const float* b4 = (const float*)d_in[13];
  const float* cls_w1 = (const float*)d_in[14]; const float* cls_b1 = (const float*)d_in[15];
  const float* prelu_a = (const float*)d_in[16];
  const float* cls_w2 = (const float*)d_in[17]; const float* cls_b2 = (const float*)d_in[18];
  float* out = (float*)d_out;

  char* ws = (char*)d_ws;
  char* R1 = ws;                        // x0 (24.2 MB) / y1 / y2 / y3
  char* R2 = ws + 24200192;             // P1 (43.0 MB) / P2 / P3
  char* wp = ws + 24200192 + 42991616;
  __hip_bfloat16* B1t = (__hip_bfloat16*)wp;  wp += 1179648;   // 1024 x 576
  __hip_bfloat16* B2t = (__hip_bfloat16*)wp;  wp += 524288;    // 512 x 512
  __hip_bfloat16* B3t = (__hip_bfloat16*)wp;  wp += 131072;    // 256 x 256
  __hip_bfloat16* B4t = (__hip_bfloat16*)wp;  wp += 32768;     // 128 x 128
  float* partial  = (float*)wp;               wp += 256 * 1152 * 4;
  float* statsbuf = (float*)wp;               wp += 1152 * 4;
  float* gbias    = (float*)wp;               wp += 1024 * 4;

  __hip_bfloat16* x0 = (__hip_bfloat16*)R1;
  __hip_bfloat16* P1 = (__hip_bfloat16*)R2;

  // K1: fused cast + stats (one pass over node_feats)
  front_kernel<<<256, 576, 0, stream>>>(node_feats, partial, x0);
  // K2: wide BN reduce
  reduce_kernel<<<3, 256, 0, stream>>>(partial, statsbuf);
  // K3: W1 fold-repack + cvec GEMV + W2-4 repack
  wt1_kernel<<<932, 256, 0, stream>>>(W1, b1, statsbuf, B1t, gbias,
                                      W2, W3, W4, B2t, B3t, B4t);

  // L1 (+ conv pool appended: 1024 blocks fill the GEMM tail)
  gemm_kernel<<<NTM2 * 8 + 1024, 256, 0, stream>>>(
      x0, B1t, gbias, 1024, P1, 1024, 576, 8, inputs, conv_w, conv_b, out);
  aggep_kernel<512><<<512, 256, 0, stream>>>(P1, Aadj, (__hip_bfloat16*)R1);
  // L2
  gemm_kernel<<<NTM2 * 4, 256, 0, stream>>>(
      (__hip_bfloat16*)R1, B2t, b2, 256, (__hip_bfloat16*)R2, 512, 512, 4,
      nullptr, nullptr, nullptr, nullptr);
  aggep_kernel<256><<<512, 256, 0, stream>>>(
      (__hip_bfloat16*)R2, Aadj, (__hip_bfloat16*)R1);
  // L3
  gemm_kernel<<<NTM2 * 2, 256, 0, stream>>>(
      (__hip_bfloat16*)R1, B3t, b3, 128, (__hip_bfloat16*)R2, 256, 256, 2,
      nullptr, nullptr, nullptr, nullptr);
  aggep_kernel<128><<<256, 256, 0, stream>>>(
      (__hip_bfloat16*)R2, Aadj, (__hip_bfloat16*)R1);
  // L4 fused: gemm + agg + knn classifier
  gemm4cls_kernel<<<171, 256, 0, stream>>>(
      (__hip_bfloat16*)R1, B4t, b4, Aadj, knn, cls_w1, cls_b1, prelu_a,
      cls_w2, cls_b2, out + 6291456);
}

// Round 11
// 249.588 us; speedup vs baseline: 1.3712x; 1.3712x over previous
//
#include <hip/hip_runtime.h>
#include <hip/hip_bf16.h>

// ---------------------------------------------------------------------------
// DRRGHead, 7 dispatches.
//   relu(cat(x_norm, A@x_norm) @ W + b) == relu(x@W' + b' + A@(x@W'_bot))
// BN folded into W1. NEW (R11): GEMM+agg fully fused per layer —
//   * M-tile = 3 graphs (123 rows, padded to 128 MFMA rows, clamped staging)
//   * Bt rows permuted so each 128-row tile = 64 L-cols + their 64 R-cols
//     (jp = (rowh>>6)*128 + h*64 + (rowh&63)); B4t layout unchanged by perm.
//   * epilogue: P -> LDS (overlay), y = relu(P_L + A@P_R) written directly.
//   Deletes aggep x3 dispatches and the P HBM round-trip (~150 MB).
// GEMM core: 128x128, 2-ph dbuf global_load_lds, conflict-free slot-swizzle
// (R8, verified 3.0M->0 conflicts), supergroup swizzle, conv tail in L1.
// ---------------------------------------------------------------------------

using f32x4 = __attribute__((ext_vector_type(4))) float;
using s16x8 = __attribute__((ext_vector_type(8))) short;   // 8 bf16

#define GN 20992          // G*N rows
#define NFEAT 576
#define NGRAPH 512
#define NNODE 41
#define NTMG 171          // m-tiles of 3 graphs (123 rows); 171*3 = 513 >= 512

typedef __attribute__((address_space(1))) const unsigned int gas_u32;
typedef __attribute__((address_space(3))) unsigned int las_u32;

__device__ __forceinline__ void gl_lds16(const void* g, void* l) {
  __builtin_amdgcn_global_load_lds((gas_u32*)g, (las_u32*)l, 16, 0, 0);
}

// ---------------- K1: fused bf16-cast + bn-stats (one pass over nf) ---------
__global__ __launch_bounds__(576) void front_kernel(
    const float* __restrict__ nf, float* __restrict__ partial,
    __hip_bfloat16* __restrict__ x0) {
  int c = threadIdx.x;                  // 0..575
  int u = blockIdx.x;                   // 0..255
  int r0 = u * 82;
  const float* src = nf + (size_t)r0 * NFEAT + c;
  __hip_bfloat16* dst = x0 + (size_t)r0 * NFEAT + c;
  float s = 0.f, s2 = 0.f;
#pragma unroll 4
  for (int r = 0; r < 82; ++r) {
    float v = src[(size_t)r * NFEAT];
    s += v; s2 += v * v;
    dst[(size_t)r * NFEAT] = __float2bfloat16(v);
  }
  partial[(size_t)u * 1152 + c] = s;
  partial[(size_t)u * 1152 + NFEAT + c] = s2;
}

// ---------------- K2: wide BN reduce -> statsbuf = {inv[576], m*inv[576]} ---
__global__ __launch_bounds__(256) void reduce_kernel(
    const float* __restrict__ partial, float* __restrict__ statsbuf) {
  int t = blockIdx.x * 256 + threadIdx.x;
  if (t >= NFEAT) return;
  float s = 0.f, s2 = 0.f;
#pragma unroll 8
  for (int u = 0; u < 256; ++u) {
    s += partial[(size_t)u * 1152 + t];
    s2 += partial[(size_t)u * 1152 + NFEAT + t];
  }
  float m = s * (1.f / GN);
  float v = s2 * (1.f / GN) - m * m;
  float inv = rsqrtf(v + 1e-5f);
  statsbuf[t] = inv;
  statsbuf[NFEAT + t] = m * inv;
}

// ---------------- K3: W1 fold-repack + cvec GEMV + W2-4 repack --------------
// All Bt writes use paired-col permutation jp = (rowh>>6)*128 + h*64 + (rowh&63)
__global__ __launch_bounds__(256) void wt1_kernel(
    const float* __restrict__ W1, const float* __restrict__ b1,
    const float* __restrict__ statsbuf, __hip_bfloat16* __restrict__ B1,
    float* __restrict__ gbias,
    const float* __restrict__ W2, const float* __restrict__ W3,
    const float* __restrict__ W4,
    __hip_bfloat16* __restrict__ B2, __hip_bfloat16* __restrict__ B3,
    __hip_bfloat16* __restrict__ B4) {
  int u = blockIdx.x;
  int tid = threadIdx.x;
  if (u < 576) {                        // fold-repack tile of W1 (2N=1024,K=576)
    __shared__ float T[32 * 33];
    int jt = u / 18, kt = u - jt * 18;
    int j0 = jt * 32, k0 = kt * 32;
    int h = (j0 >= 512) ? 1 : 0;
    const float* Wh = W1 + (size_t)(h * 576) * 512 + (j0 - h * 512);
    int r = tid >> 5, cc = tid & 31;
#pragma unroll
    for (int i = 0; i < 4; ++i)
      T[(r + i * 8) * 33 + cc] = Wh[(size_t)(k0 + r + i * 8) * 512 + cc];
    __syncthreads();
    float invv = statsbuf[k0 + cc];
#pragma unroll
    for (int i = 0; i < 4; ++i) {
      int rowh = (j0 - h * 512) + r + i * 8;
      int jp = (rowh >> 6) * 128 + h * 64 + (rowh & 63);
      B1[(size_t)jp * 576 + k0 + cc] =
          __float2bfloat16(T[cc * 33 + (r + i * 8)] * invv);
    }
  } else if (u < 580) {                 // cvec GEMV (gbias in ORIGINAL order)
    int j = (u - 576) * 256 + tid;      // 0..1023
    int col = (j < 512) ? j : j - 512;
    const float* base = W1 + (size_t)((j < 512) ? 0 : 576) * 512 + col;
    float s = 0.f;
#pragma unroll 4
    for (int f = 0; f < NFEAT; ++f) s += statsbuf[NFEAT + f] * base[(size_t)f * 512];
    gbias[j] = ((j < 512) ? b1[j] : 0.f) - s;
  } else {                              // plain repack W2/W3/W4 (permuted rows)
    __shared__ float T[32 * 33];
    int t = u - 580;
    const float* W; __hip_bfloat16* B; int K, N;
    if (t < 256)      { W = W2; B = B2; K = 512; N = 256; }
    else if (t < 320) { W = W3; B = B3; K = 256; N = 128; t -= 256; }
    else              { W = W4; B = B4; K = 128; N = 64;  t -= 320; }
    int tilesN = N >> 5;
    int perhalf = (K >> 5) * tilesN;
    int h = t / perhalf; t -= h * perhalf;
    int tk = t / tilesN, tn = t - tk * tilesN;
    int r = tid >> 5, cc = tid & 31;
    const float* Wh = W + (size_t)h * K * N;
#pragma unroll
    for (int i = 0; i < 4; ++i)
      T[(r + i * 8) * 33 + cc] = Wh[(size_t)(tk * 32 + r + i * 8) * N + tn * 32 + cc];
    __syncthreads();
#pragma unroll
    for (int i = 0; i < 4; ++i) {
      int row = tn * 32 + r + i * 8;
      int jp = (row >> 6) * 128 + h * 64 + (row & 63);
      B[(size_t)jp * K + tk * 32 + cc] =
          __float2bfloat16(T[cc * 33 + r + i * 8]);
    }
  }
}

// ---------------- fused GEMM + agg: y = relu(P_L + A@P_R), layers 1-3 -------
// M-tile = 3 graphs (123 rows pad 128); N-tile = 64 L-cols + 64 paired R-cols.
// P kept in LDS (overlay on staging); y written directly. Conv tail in L1.
__global__ __launch_bounds__(256) void gemmagg_kernel(
    const __hip_bfloat16* __restrict__ Xptr, const __hip_bfloat16* __restrict__ Bt,
    const float* __restrict__ biasL, const float* __restrict__ biasR,
    __hip_bfloat16* __restrict__ Yptr, int Nout, int K, int NTN,
    const float* __restrict__ Aadj,
    const float* __restrict__ cinputs, const float* __restrict__ conv_w,
    const float* __restrict__ conv_b, float* __restrict__ cout) {
  // LDS: [0,32768) staging dbuf (A 16KB + B 16KB); Psh 128x128 bf16 overlays;
  //      Aash above.
  __shared__ __align__(16) char smem[32768 + 20172];
  short* AshD = (short*)smem;                 // [2][128*32]
  short* BshD = (short*)(smem + 16384);       // [2][128*32]
  __hip_bfloat16* Psh = (__hip_bfloat16*)smem;
  float* Aash = (float*)(smem + 32768);

  int tid = threadIdx.x;
  int bid = blockIdx.x;
  int gemmBlocks = NTMG * NTN;

  if (bid >= gemmBlocks) {              // ---- conv pool (tail filler, L1 only)
    int p = (bid - gemmBlocks) * 256 + tid;
    int img = p >> 16, q = p & 65535;
    const float4* ip = (const float4*)cinputs + (size_t)img * 32 * 65536 + q;
    float4 acc[6];
#pragma unroll
    for (int o = 0; o < 6; ++o) { float b0 = conv_b[o]; acc[o] = make_float4(b0, b0, b0, b0); }
#pragma unroll 4
    for (int c = 0; c < 32; ++c) {
      float4 x = ip[(size_t)c * 65536];
#pragma unroll
      for (int o = 0; o < 6; ++o) {
        float wv = conv_w[o * 32 + c];
        acc[o].x += x.x * wv; acc[o].y += x.y * wv;
        acc[o].z += x.z * wv; acc[o].w += x.w * wv;
      }
    }
    float4* op = (float4*)cout + (size_t)img * 6 * 65536 + q;
#pragma unroll
    for (int o = 0; o < 6; ++o) op[(size_t)o * 65536] = acc[o];
    return;
  }

  int sg = bid / (NTN * 8);
  int rem = bid - sg * (NTN * 8);
  int Wm = NTMG - sg * 8; if (Wm > 8) Wm = 8;
  int mt = sg * 8 + rem % Wm;
  int nt = rem / Wm;
  int row0 = mt * 123;
  int g0 = mt * 3;
  int gcnt = NGRAPH - g0; if (gcnt > 3) gcnt = 3;

  // adjacency for this block's graphs (ds_writes; visible after first barrier)
  for (int i = tid; i < gcnt * NNODE * NNODE; i += 256)
    Aash[i] = Aadj[(size_t)g0 * (NNODE * NNODE) + i];

  int wave = tid >> 6, lane = tid & 63;
  int wm = wave >> 1, wn = wave & 1;
  int lr = lane & 15, kb = lane >> 4;

  f32x4 acc[4][4];
#pragma unroll
  for (int m = 0; m < 4; ++m)
#pragma unroll
    for (int n = 0; n < 4; ++n) acc[m][n] = (f32x4){0.f, 0.f, 0.f, 0.f};

  const short* Ag = (const short*)Xptr;
  const short* Bg = (const short*)Bt + (size_t)nt * 128 * K;

  // staging: slot c holds global chunk (row = c>>2, k-chunk = (c&3)^((row>>1)&3))
  int c0 = tid, c1 = tid + 256;
  int ar0 = c0 >> 2, ak0 = (((c0 & 3) ^ ((ar0 >> 1) & 3))) * 8;
  int ar1 = c1 >> 2, ak1 = (((c1 & 3) ^ ((ar1 >> 1) & 3))) * 8;
  int grow0 = row0 + ar0; if (grow0 > GN - 1) grow0 = GN - 1;   // pad rows clamp
  int grow1 = row0 + ar1; if (grow1 > GN - 1) grow1 = GN - 1;

  // fragment read offsets (shorts): row*32 + (((row>>1)&3)^kb)*8
  int aoff[4], boff[4];
#pragma unroll
  for (int m = 0; m < 4; ++m) {
    int r = wm * 64 + m * 16 + lr;
    aoff[m] = r * 32 + ((((r >> 1) & 3) ^ kb) * 8);
  }
#pragma unroll
  for (int n = 0; n < 4; ++n) {
    int r = wn * 64 + n * 16 + lr;
    boff[n] = r * 32 + ((((r >> 1) & 3) ^ kb) * 8);
  }

  gl_lds16(Ag + (size_t)grow0 * K + ak0, &AshD[c0 * 8]);
  gl_lds16(Ag + (size_t)grow1 * K + ak1, &AshD[c1 * 8]);
  gl_lds16(Bg + (size_t)ar0 * K + ak0, &BshD[c0 * 8]);
  gl_lds16(Bg + (size_t)ar1 * K + ak1, &BshD[c1 * 8]);
  __syncthreads();

  int nkt = K >> 5;
  int cur = 0;
  for (int kt = 0; kt < nkt; ++kt) {
    if (kt + 1 < nkt) {
      int k1 = (kt + 1) * 32;
      int nxt = (cur ^ 1) * 4096;
      gl_lds16(Ag + (size_t)grow0 * K + k1 + ak0, &AshD[nxt + c0 * 8]);
      gl_lds16(Ag + (size_t)grow1 * K + k1 + ak1, &AshD[nxt + c1 * 8]);
      gl_lds16(Bg + (size_t)ar0 * K + k1 + ak0, &BshD[nxt + c0 * 8]);
      gl_lds16(Bg + (size_t)ar1 * K + k1 + ak1, &BshD[nxt + c1 * 8]);
    }
    int cb = cur * 4096;
    s16x8 af[4], bfr[4];
#pragma unroll
    for (int m = 0; m < 4; ++m) af[m] = *(const s16x8*)&AshD[cb + aoff[m]];
#pragma unroll
    for (int n = 0; n < 4; ++n) bfr[n] = *(const s16x8*)&BshD[cb + boff[n]];
#pragma unroll
    for (int m = 0; m < 4; ++m)
#pragma unroll
      for (int n = 0; n < 4; ++n)
        acc[m][n] = __builtin_amdgcn_mfma_f32_16x16x32_bf16(af[m], bfr[n], acc[m][n], 0, 0, 0);
    __syncthreads();
    cur ^= 1;
  }

  // epilogue 1: P (+bias, both halves) -> Psh overlay (safe: loop ended w/ barrier)
  int rbase = (lane >> 4) * 4;
#pragma unroll
  for (int m = 0; m < 4; ++m) {
    int lrow = wm * 64 + m * 16 + rbase;
#pragma unroll
    for (int n = 0; n < 4; ++n) {
      int w = wn * 64 + n * 16 + lr;
      float bv = (w < 64) ? biasL[nt * 64 + w]
                          : (biasR ? biasR[nt * 64 + (w - 64)] : 0.f);
#pragma unroll
      for (int r = 0; r < 4; ++r)
        Psh[(size_t)(lrow + r) * 128 + w] = __float2bfloat16(acc[m][n][r] + bv);
    }
  }
  __syncthreads();

  // epilogue 2: y[g][n][c] = relu(P_L[n][c] + sum_m A[n][m] * P_R[m][c])
  int c = tid & 63, grp = tid >> 6;
  for (int g = 0; g < gcnt; ++g) {
    float pr[NNODE];
#pragma unroll
    for (int m = 0; m < NNODE; ++m)
      pr[m] = __bfloat162float(Psh[(size_t)(g * NNODE + m) * 128 + 64 + c]);
    const float* Am = Aash + g * NNODE * NNODE;
#pragma unroll 1
    for (int n = grp; n < NNODE; n += 4) {
      float aa = __bfloat162float(Psh[(size_t)(g * NNODE + n) * 128 + c]);
#pragma unroll
      for (int m = 0; m < NNODE; ++m) aa += Am[n * NNODE + m] * pr[m];
      aa = aa > 0.f ? aa : 0.f;
      Yptr[(size_t)(row0 + g * NNODE + n) * Nout + nt * 64 + c] = __float2bfloat16(aa);
    }
  }
}

// ---------------- G4F: gemm4 + agg4 + knn classifier, 3 graphs/block --------
__global__ __launch_bounds__(256) void gemm4cls_kernel(
    const __hip_bfloat16* __restrict__ X, const __hip_bfloat16* __restrict__ B4t,
    const float* __restrict__ b4, const float* __restrict__ Aadj,
    const int* __restrict__ knn, const float* __restrict__ w1,
    const float* __restrict__ cb1, const float* __restrict__ pa,
    const float* __restrict__ w2, const float* __restrict__ cb2,
    float* __restrict__ out) {
  __shared__ __align__(16) char smem[49152 + 20172 + 31488 + 8192 + 520];
  short* AshD = (short*)smem;
  short* Bsh  = (short*)(smem + 16384);
  __hip_bfloat16* Psh = (__hip_bfloat16*)smem;
  float* Aash = (float*)(smem + 49152);
  float* Ysh  = (float*)(smem + 49152 + 20172);
  float* Wsh  = (float*)(smem + 49152 + 20172 + 31488);
  float* cb   = (float*)(smem + 49152 + 20172 + 31488 + 8192);

  int tid = threadIdx.x;
  int blk = blockIdx.x;
  int g0 = blk * 3;
  int gcnt = NGRAPH - g0; if (gcnt > 3) gcnt = 3;
  int row0 = blk * 123;

  for (int i = tid; i < gcnt * NNODE * NNODE; i += 256)
    Aash[i] = Aadj[(size_t)g0 * (NNODE * NNODE) + i];
  for (int i = tid; i < 2048; i += 256) Wsh[i] = w1[i];
  if (tid < 32) { cb[tid] = cb1[tid]; cb[32 + tid] = pa[tid]; }
  if (tid < 64) cb[64 + tid] = w2[tid];
  if (tid < 2) cb[128 + tid] = cb2[tid];

  // stage whole B4t (4 ktiles), slot-swizzled within each ktile
#pragma unroll
  for (int i = 0; i < 8; ++i) {
    int c = tid + i * 256;              // 2048 chunks of 16B
    int kt = c >> 9, w = c & 511;
    int r = w >> 2, kc = ((w & 3) ^ ((r >> 1) & 3)) * 8;
    gl_lds16((const short*)B4t + (size_t)r * 128 + kt * 32 + kc, &Bsh[c * 8]);
  }
  // stage A k-tile 0 (swizzled)
  const short* Ag = (const short*)X;
  int c0 = tid, c1 = tid + 256;
  int ar0 = c0 >> 2, ak0 = (((c0 & 3) ^ ((ar0 >> 1) & 3))) * 8;
  int ar1 = c1 >> 2, ak1 = (((c1 & 3) ^ ((ar1 >> 1) & 3))) * 8;
  int grow0 = row0 + ar0; if (grow0 > GN - 1) grow0 = GN - 1;
  int grow1 = row0 + ar1; if (grow1 > GN - 1) grow1 = GN - 1;
  gl_lds16(Ag + (size_t)grow0 * 128 + ak0, &AshD[c0 * 8]);
  gl_lds16(Ag + (size_t)grow1 * 128 + ak1, &AshD[c1 * 8]);
  __syncthreads();

  int wave = tid >> 6, lane = tid & 63;
  int wm = wave >> 1, wn = wave & 1;
  int lr = lane & 15, kb = lane >> 4;
  int aoff[4], boff[4];
#pragma unroll
  for (int m = 0; m < 4; ++m) {
    int r = wm * 64 + m * 16 + lr;
    aoff[m] = r * 32 + ((((r >> 1) & 3) ^ kb) * 8);
  }
#pragma unroll
  for (int n = 0; n < 4; ++n) {
    int r = wn * 64 + n * 16 + lr;
    boff[n] = r * 32 + ((((r >> 1) & 3) ^ kb) * 8);
  }
  f32x4 acc[4][4];
#pragma unroll
  for (int m = 0; m < 4; ++m)
#pragma unroll
    for (int n = 0; n < 4; ++n) acc[m][n] = (f32x4){0.f, 0.f, 0.f, 0.f};

  int cur = 0;
  for (int kt = 0; kt < 4; ++kt) {
    if (kt < 3) {
      int k1 = (kt + 1) * 32;
      int nxt = (cur ^ 1) * 4096;
      gl_lds16(Ag + (size_t)grow0 * 128 + k1 + ak0, &AshD[nxt + c0 * 8]);
      gl_lds16(Ag + (size_t)grow1 * 128 + k1 + ak1, &AshD[nxt + c1 * 8]);
    }
    int cbse = cur * 4096;
    s16x8 af[4], bfr[4];
#pragma unroll
    for (int m = 0; m < 4; ++m) af[m] = *(const s16x8*)&AshD[cbse + aoff[m]];
#pragma unroll
    for (int n = 0; n < 4; ++n) bfr[n] = *(const s16x8*)&Bsh[kt * 4096 + boff[n]];
#pragma unroll
    for (int m = 0; m < 4; ++m)
#pragma unroll
      for (int n = 0; n < 4; ++n)
        acc[m][n] = __builtin_amdgcn_mfma_f32_16x16x32_bf16(af[m], bfr[n], acc[m][n], 0, 0, 0);
    __syncthreads();
    cur ^= 1;
  }
  // epilogue -> Psh
  int rbase = (lane >> 4) * 4;
#pragma unroll
  for (int m = 0; m < 4; ++m) {
    int lrow = wm * 64 + m * 16 + rbase;
#pragma unroll
    for (int n = 0; n < 4; ++n) {
      int col = wn * 64 + n * 16 + lr;
      float bv = (col < 64) ? b4[col] : 0.f;
#pragma unroll
      for (int r = 0; r < 4; ++r)
        Psh[(size_t)(lrow + r) * 128 + col] = __float2bfloat16(acc[m][n][r] + bv);
    }
  }
  __syncthreads();

  // agg into Ysh
  int c = tid & 63, grp = tid >> 6;
  for (int g = 0; g < gcnt; ++g) {
    float pr[NNODE];
#pragma unroll
    for (int m = 0; m < NNODE; ++m)
      pr[m] = __bfloat162float(Psh[(size_t)(g * NNODE + m) * 128 + 64 + c]);
    const float* Am = Aash + g * NNODE * NNODE;
#pragma unroll 1
    for (int n = grp; n < NNODE; n += 4) {
      float aa = __bfloat162float(Psh[(size_t)(g * NNODE + n) * 128 + c]);
#pragma unroll
      for (int m = 0; m < NNODE; ++m) aa += Am[n * NNODE + m] * pr[m];
      Ysh[(g * NNODE + n) * 64 + c] = aa > 0.f ? aa : 0.f;
    }
  }
  __syncthreads();

  // classifier: 8*gcnt edges, 32 lanes each
  int j = tid & 31, slot = tid >> 5;
  for (int el = slot; el < 8 * gcnt; el += 8) {
    int e = g0 * 8 + el;
    int node = knn[e];
    int gl = el >> 3;
    const float* fp = &Ysh[(gl * NNODE + node) * 64];
    float a2 = cb[j];
#pragma unroll
    for (int d = 0; d < 64; ++d) a2 += fp[d] * Wsh[d * 32 + j];
    float h = a2 >= 0.f ? a2 : cb[32 + j] * a2;
#pragma unroll
    for (int o = 0; o < 2; ++o) {
      float v = h * cb[64 + j * 2 + o];
      v += __shfl_xor(v, 16, 32); v += __shfl_xor(v, 8, 32);
      v += __shfl_xor(v, 4, 32);  v += __shfl_xor(v, 2, 32);
      v += __shfl_xor(v, 1, 32);
      if (j == 0) out[(size_t)e * 2 + o] = v;
    }
  }
}

// ---------------------------------------------------------------------------
extern "C" void kernel_launch(void* const* d_in, const int* in_sizes, int n_in,
                              void* d_out, int out_size, void* d_ws, size_t ws_size,
                              hipStream_t stream) {
  const float* inputs     = (const float*)d_in[0];
  const float* node_feats = (const float*)d_in[1];
  const float* Aadj       = (const float*)d_in[2];
  const int*   knn        = (const int*)d_in[3];
  const float* conv_w     = (const float*)d_in[4];
  const float* conv_b     = (const float*)d_in[5];
  const float* W1 = (const float*)d_in[6];  const float* b1 = (const float*)d_in[7];
  const float* W2 = (const float*)d_in[8];  const float* b2 = (const float*)d_in[9];
  const float* W3 = (const float*)d_in[10]; const float* b3 = (const float*)d_in[11];
  const float* W4 = (const float*)d_in[12]; const float* b4 = (const float*)d_in[13];
  const float* cls_w1 = (const float*)d_in[14]; const float* cls_b1 = (const float*)d_in[15];
  const float* prelu_a = (const float*)d_in[16];
  const float* cls_w2 = (const float*)d_in[17]; const float* cls_b2 = (const float*)d_in[18];
  float* out = (float*)d_out;

  char* ws = (char*)d_ws;
  char* R1 = ws;                        // x0 (24.2 MB) -> y2 (10.7 MB)
  char* R2 = ws + 24200192;             // y1 (21.5 MB) -> y3 (5.4 MB)
  char* wp = ws + 24200192 + 42991616;
  __hip_bfloat16* B1t = (__hip_bfloat16*)wp;  wp += 1179648;   // 1024 x 576
  __hip_bfloat16* B2t = (__hip_bfloat16*)wp;  wp += 524288;    // 512 x 512
  __hip_bfloat16* B3t = (__hip_bfloat16*)wp;  wp += 131072;    // 256 x 256
  __hip_bfloat16* B4t = (__hip_bfloat16*)wp;  wp += 32768;     // 128 x 128
  float* partial  = (float*)wp;               wp += 256 * 1152 * 4;
  float* statsbuf = (float*)wp;               wp += 1152 * 4;
  float* gbias    = (float*)wp;               wp += 1024 * 4;

  __hip_bfloat16* x0 = (__hip_bfloat16*)R1;

  // K1: fused cast + stats (one pass over node_feats)
  front_kernel<<<256, 576, 0, stream>>>(node_feats, partial, x0);
  // K2: wide BN reduce
  reduce_kernel<<<3, 256, 0, stream>>>(partial, statsbuf);
  // K3: W1 fold-repack + cvec GEMV + W2-4 repack (paired-col permutation)
  wt1_kernel<<<932, 256, 0, stream>>>(W1, b1, statsbuf, B1t, gbias,
                                      W2, W3, W4, B2t, B3t, B4t);

  // L1 fused gemm+agg (+ conv tail): x0 -> y1 (R2), Nout=512, K=576, NTN=8
  gemmagg_kernel<<<NTMG * 8 + 1024, 256, 0, stream>>>(
      x0, B1t, gbias, gbias + 512, (__hip_bfloat16*)R2, 512, 576, 8, Aadj,
      inputs, conv_w, conv_b, out);
  // L2: y1 -> y2 (R1), Nout=256, K=512, NTN=4
  gemmagg_kernel<<<NTMG * 4, 256, 0, stream>>>(
      (__hip_bfloat16*)R2, B2t, b2, nullptr, (__hip_bfloat16*)R1, 256, 512, 4,
      Aadj, nullptr, nullptr, nullptr, nullptr);
  // L3: y2 -> y3 (R2), Nout=128, K=256, NTN=2
  gemmagg_kernel<<<NTMG * 2, 256, 0, stream>>>(
      (__hip_bfloat16*)R1, B3t, b3, nullptr, (__hip_bfloat16*)R2, 128, 256, 2,
      Aadj, nullptr, nullptr, nullptr, nullptr);
  // L4 fused: gemm + agg + knn classifier
  gemm4cls_kernel<<<171, 256, 0, stream>>>(
      (__hip_bfloat16*)R2, B4t, b4, Aadj, knn, cls_w1, cls_b1, prelu_a,
      cls_w2, cls_b2, out + 6291456);
}